// Round 2
// baseline (137.267 us; speedup 1.0000x reference)
//
#include <hip/hip_runtime.h>
#include <hip/hip_bf16.h>

// out[b,m,n] = sum_k fq(x1)[b,m,k] * fq(x2)[b,k,n], B=8 M=4096 K=64 N=4096.
// fq maps every value to code/255, code in [0,255] -> codes exact in bf16.
// Single fused kernel: quantize inline while staging, in-LDS transpose for
// x2, exact integer bf16 MFMA, scale f32 accum by (c1/255)(c2/255) at store.
// Roofline: 512MB f32 output write ~76us at 6.7TB/s achieved. Write-bound.

#define BATCH 8
#define MDIM 4096
#define KDIM 64
#define NDIM 4096
#define TMPS 132   // Tmp row stride in u16 (pad: k-stride -> alternating banks)

typedef __attribute__((ext_vector_type(4))) unsigned short u16x4;
typedef __attribute__((ext_vector_type(8))) short s16x8;
typedef __attribute__((ext_vector_type(4))) float f32x4;

// quantize x -> integer code (0..level-1) as bf16 bit pattern (exact:
// integers 0..255 have zero low-mantissa bits in f32)
__device__ __forceinline__ unsigned short qcode(float x, float c, float inv) {
    float xc = fminf(fmaxf(x, 0.0f), c);
    float k = rintf(xc * inv);            // round-half-even == np.round
    return (unsigned short)(__float_as_uint(k) >> 16);
}

__device__ __forceinline__ s16x8 qpack(float4 v0, float4 v1, float c, float inv) {
    s16x8 o;
    o[0] = (short)qcode(v0.x, c, inv);
    o[1] = (short)qcode(v0.y, c, inv);
    o[2] = (short)qcode(v0.z, c, inv);
    o[3] = (short)qcode(v0.w, c, inv);
    o[4] = (short)qcode(v1.x, c, inv);
    o[5] = (short)qcode(v1.y, c, inv);
    o[6] = (short)qcode(v1.z, c, inv);
    o[7] = (short)qcode(v1.w, c, inv);
    return o;
}

// One fused kernel: 128x128 output tile, full K=64 staged once, 4 waves
// (2x2), each wave 64x64 via 4x4 grid of 16x16x32 bf16 MFMA fragments.
__global__ __launch_bounds__(256)
void fq_gemm(const float* __restrict__ x1, const float* __restrict__ x2,
             const float* __restrict__ c1p, const float* __restrict__ c2p,
             const int* __restrict__ lvp, float* __restrict__ out) {
    __shared__ unsigned short As[128 * 64];    // [m][k] codes, XOR-swizzled
    __shared__ unsigned short Bs[128 * 64];    // [n][k] codes, XOR-swizzled
    __shared__ unsigned short Tmp[64 * TMPS];  // [k][n] codes, padded

    const int b = blockIdx.z, mt = blockIdx.y, nt = blockIdx.x;
    const int t = threadIdx.x;

    const float c1 = c1p[0], c2 = c2p[0];
    const float lvm1 = (float)(lvp[0] - 1);
    const float inv1 = lvm1 / c1, inv2 = lvm1 / c2;

    // ---- stage A: x1 f32 [128 m][64 k] -> quantize -> As[m][k] swizzled
    const float* gA = x1 + ((size_t)b * MDIM + mt * 128) * KDIM;
#pragma unroll
    for (int it = 0; it < 4; ++it) {
        int qi = t + it * 256;                 // [0,1024): m = qi>>3, c8 = qi&7
        int m = qi >> 3, c8 = qi & 7;
        const float* p = gA + (size_t)m * KDIM + c8 * 8;
        float4 v0 = *(const float4*)p;
        float4 v1 = *(const float4*)(p + 4);
        int off = (m * 128 + c8 * 16) ^ ((m & 7) << 4);
        *(s16x8*)((char*)As + off) = qpack(v0, v1, c1, inv1);
    }

    // ---- stage B1: x2 f32 [64 k][128 n] -> quantize -> Tmp[k][n]
    const float* gB = x2 + (size_t)b * KDIM * NDIM + nt * 128;
#pragma unroll
    for (int it = 0; it < 4; ++it) {
        int qi = t + it * 256;                 // k = qi>>4, n0 = (qi&15)*8
        int k = qi >> 4, c8 = qi & 15;
        const float* p = gB + (size_t)k * NDIM + c8 * 8;
        float4 v0 = *(const float4*)p;
        float4 v1 = *(const float4*)(p + 4);
        s16x8 o = qpack(v0, v1, c2, inv2);
        // row stride 132 u16 = 264B: only 8B-aligned -> two b64 writes
        char* q = (char*)Tmp + (size_t)k * (TMPS * 2) + c8 * 16;
        u16x4 lo, hi;
        lo[0] = o[0]; lo[1] = o[1]; lo[2] = o[2]; lo[3] = o[3];
        hi[0] = o[4]; hi[1] = o[5]; hi[2] = o[6]; hi[3] = o[7];
        *(u16x4*)q = lo;
        *(u16x4*)(q + 8) = hi;
    }
    __syncthreads();

    // ---- stage B2: transpose Tmp[k][n] -> Bs[n][k] swizzled
#pragma unroll
    for (int it = 0; it < 4; ++it) {
        int qi = t + it * 256;                 // n = qi>>3, k0 = (qi&7)*8
        int n = qi >> 3, k8 = qi & 7, k0 = k8 * 8;
        s16x8 o;
#pragma unroll
        for (int j = 0; j < 8; ++j)
            o[j] = (short)Tmp[(size_t)(k0 + j) * TMPS + n];
        int off = (n * 128 + k8 * 16) ^ ((n & 7) << 4);
        *(s16x8*)((char*)Bs + off) = o;
    }
    __syncthreads();

    // ---- MFMA: wave (2x2) owns 64x64; 4x4 fragments x 2 k-steps
    const int lane = t & 63, w = t >> 6;
    const int wr = (w >> 1) * 64, wc = (w & 1) * 64;
    const int r16 = lane & 15, kq = lane >> 4;

    f32x4 acc[4][4] = {};
#pragma unroll
    for (int ks = 0; ks < 2; ++ks) {
        const int kb = ks * 64 + kq * 16;      // byte offset of lane's k-slice
        s16x8 a[4], bf[4];
#pragma unroll
        for (int mf = 0; mf < 4; ++mf) {
            int row = wr + mf * 16 + r16;
            int off = (row * 128 + kb) ^ ((row & 7) << 4);
            a[mf] = *(const s16x8*)((const char*)As + off);
        }
#pragma unroll
        for (int nf = 0; nf < 4; ++nf) {
            int row = wc + nf * 16 + r16;
            int off = (row * 128 + kb) ^ ((row & 7) << 4);
            bf[nf] = *(const s16x8*)((const char*)Bs + off);
        }
#pragma unroll
        for (int mf = 0; mf < 4; ++mf)
#pragma unroll
            for (int nf = 0; nf < 4; ++nf)
                acc[mf][nf] = __builtin_amdgcn_mfma_f32_16x16x32_bf16(
                    a[mf], bf[nf], acc[mf][nf], 0, 0, 0);
    }

    // ---- epilogue: scale integer-code accum, coalesced dword stores
    const float s = (c1 / lvm1) * (c2 / lvm1);
    size_t obase = (size_t)b * MDIM * NDIM;
    int m0 = mt * 128 + wr, n0 = nt * 128 + wc;
#pragma unroll
    for (int mf = 0; mf < 4; ++mf) {
#pragma unroll
        for (int i = 0; i < 4; ++i) {
            int m = m0 + mf * 16 + kq * 4 + i;
            float* orow = out + obase + (size_t)m * NDIM + n0 + r16;
#pragma unroll
            for (int nf = 0; nf < 4; ++nf)
                orow[nf * 16] = acc[mf][nf][i] * s;
        }
    }
}

extern "C" void kernel_launch(void* const* d_in, const int* in_sizes, int n_in,
                              void* d_out, int out_size, void* d_ws, size_t ws_size,
                              hipStream_t stream) {
    const float* x1 = (const float*)d_in[0];
    const float* x2 = (const float*)d_in[1];
    const float* c1 = (const float*)d_in[2];
    const float* c2 = (const float*)d_in[3];
    const int* lv   = (const int*)d_in[4];
    float* out = (float*)d_out;

    fq_gemm<<<dim3(NDIM / 128, MDIM / 128, BATCH), 256, 0, stream>>>(
        x1, x2, c1, c2, lv, out);
}

// Round 3
// 133.360 us; speedup vs baseline: 1.0293x; 1.0293x over previous
//
#include <hip/hip_runtime.h>
#include <hip/hip_bf16.h>

// out[b,m,n] = sum_k fq(x1)[b,m,k] * fq(x2)[b,k,n], B=8 M=4096 K=64 N=4096.
// fq maps every value to code/255, code in [0,255] -> codes exact in bf16.
// Split design (quantize ONCE, then GEMM): kernel1 quantizes A (straight)
// and B (transposed to [n][k] via LDS tile) into ws as bf16 integer codes;
// kernel2 is an LDS-free MFMA GEMM loading fragments directly from global
// (both operands K-contiguous), f32 accum scaled by (c1/255)(c2/255).
// Roofline: 512MB f32 output write ~76us at 6.7TB/s achieved. Write-bound.

#define BATCH 8
#define MDIM 4096
#define KDIM 64
#define NDIM 4096

typedef __attribute__((ext_vector_type(4))) unsigned short u16x4;
typedef __attribute__((ext_vector_type(8))) short s16x8;
typedef __attribute__((ext_vector_type(4))) float f32x4;

// quantize x -> integer code (0..level-1) as bf16 bit pattern (exact:
// integers 0..255 have zero low-mantissa bits in f32)
__device__ __forceinline__ unsigned short qcode(float x, float c, float inv) {
    float xc = fminf(fmaxf(x, 0.0f), c);
    float k = rintf(xc * inv);            // round-half-even == np.round
    return (unsigned short)(__float_as_uint(k) >> 16);
}

// ---- kernel 1: quantize A [B,M,K]->codes (same layout), and B [B,K,N] ->
// codes transposed [B,N,K]. Block-range dispatch: first QA_BLOCKS blocks do
// A (pure elementwise), the rest do 64x64 B tiles through LDS.
#define QA_BLOCKS 2048   // 2M f32 elems / (256 thr * 4 elems)

__global__ void quant_both(const float* __restrict__ x1, const float* __restrict__ x2,
                           unsigned short* __restrict__ qA, unsigned short* __restrict__ qBt,
                           const float* __restrict__ c1p, const float* __restrict__ c2p,
                           const int* __restrict__ lvp) {
    __shared__ unsigned short T[64 * 68];   // B path only; pad 68 spreads banks
    const int t = threadIdx.x;
    const float lvm1 = (float)(lvp[0] - 1);

    if (blockIdx.x < QA_BLOCKS) {
        // ---- A path: x1 f32 -> bf16 codes, 1 float4 per thread
        const float c = c1p[0], inv = lvm1 / c;
        int i = blockIdx.x * 256 + t;
        float4 v = ((const float4*)x1)[i];
        u16x4 o;
        o[0] = qcode(v.x, c, inv);
        o[1] = qcode(v.y, c, inv);
        o[2] = qcode(v.z, c, inv);
        o[3] = qcode(v.w, c, inv);
        ((u16x4*)qA)[i] = o;
        return;
    }

    // ---- B path: quantize + transpose one [64 k][64 n] tile
    const float c = c2p[0], inv = lvm1 / c;
    int bi = blockIdx.x - QA_BLOCKS;        // [0, 512)
    int b = bi >> 6;                        // batch
    int n0 = (bi & 63) * 64;                // n tile origin

    const float* src = x2 + (size_t)b * KDIM * NDIM + n0;
#pragma unroll
    for (int it = 0; it < 4; ++it) {
        int qi = t + it * 256;
        int k = qi >> 4, c4 = qi & 15;      // 64 rows x 16 float4
        float4 v = *(const float4*)(src + (size_t)k * NDIM + c4 * 4);
        u16x4 o;
        o[0] = qcode(v.x, c, inv);
        o[1] = qcode(v.y, c, inv);
        o[2] = qcode(v.z, c, inv);
        o[3] = qcode(v.w, c, inv);
        *(u16x4*)&T[k * 68 + c4 * 4] = o;
    }
    __syncthreads();

    unsigned short* dst = qBt + ((size_t)b * NDIM + n0) * KDIM;
#pragma unroll
    for (int it = 0; it < 4; ++it) {
        int qi = t + it * 256;
        int n = qi >> 4, c4 = qi & 15;      // 64 out-rows x 16 chunks of 4 k
        u16x4 o;
        o[0] = T[(c4 * 4 + 0) * 68 + n];
        o[1] = T[(c4 * 4 + 1) * 68 + n];
        o[2] = T[(c4 * 4 + 2) * 68 + n];
        o[3] = T[(c4 * 4 + 3) * 68 + n];
        *(u16x4*)(dst + (size_t)n * KDIM + c4 * 4) = o;
    }
}

// ---- kernel 2: LDS-free GEMM. 128x128 tile, 4 waves (2x2), each wave
// 64x64 via 4x4 grid of 16x16x32 bf16 MFMA fragments loaded straight from
// global (dwordx4, L2-resident). Swapped operands -> float4 output stores.
__global__ __launch_bounds__(256)
void gemm_q(const unsigned short* __restrict__ qA, const unsigned short* __restrict__ qBt,
            const float* __restrict__ c1p, const float* __restrict__ c2p,
            const int* __restrict__ lvp, float* __restrict__ out) {
    const int b = blockIdx.z, mt = blockIdx.y, nt = blockIdx.x;
    const int t = threadIdx.x;
    const int lane = t & 63, w = t >> 6;
    const int wr = (w >> 1) * 64, wc = (w & 1) * 64;   // wave 64x64 sub-tile
    const int r16 = lane & 15, kq = lane >> 4;

    // lane base pointers: row = (tile + wave + r16), k = kq*8
    const unsigned short* pA =
        qA + ((size_t)b * MDIM + mt * 128 + wr + r16) * KDIM + kq * 8;
    const unsigned short* pB =
        qBt + ((size_t)b * NDIM + nt * 128 + wc + r16) * KDIM + kq * 8;

    f32x4 acc[4][4] = {};
#pragma unroll
    for (int ks = 0; ks < 2; ++ks) {
        s16x8 a[4], bf[4];
#pragma unroll
        for (int mf = 0; mf < 4; ++mf)
            a[mf] = *(const s16x8*)(pA + mf * 16 * KDIM + ks * 32);
#pragma unroll
        for (int nf = 0; nf < 4; ++nf)
            bf[nf] = *(const s16x8*)(pB + nf * 16 * KDIM + ks * 32);
        // swapped operands: D[row=n][col=m] -> lane holds 4 consecutive n
#pragma unroll
        for (int mf = 0; mf < 4; ++mf)
#pragma unroll
            for (int nf = 0; nf < 4; ++nf)
                acc[mf][nf] = __builtin_amdgcn_mfma_f32_16x16x32_bf16(
                    bf[nf], a[mf], acc[mf][nf], 0, 0, 0);
    }

    // epilogue: scale integer-code accum, one float4 store per fragment
    const float c1 = c1p[0], c2 = c2p[0];
    const float lvm1 = (float)(lvp[0] - 1);
    const float s = (c1 / lvm1) * (c2 / lvm1);

    size_t obase = (size_t)b * MDIM * NDIM;
    const int m0 = mt * 128 + wr, n0 = nt * 128 + wc;
#pragma unroll
    for (int mf = 0; mf < 4; ++mf) {
        int m = m0 + mf * 16 + r16;
        float* orow = out + obase + (size_t)m * NDIM;
#pragma unroll
        for (int nf = 0; nf < 4; ++nf) {
            int nb = n0 + nf * 16 + kq * 4;
            float4 v;
            v.x = acc[mf][nf][0] * s;
            v.y = acc[mf][nf][1] * s;
            v.z = acc[mf][nf][2] * s;
            v.w = acc[mf][nf][3] * s;
            *(float4*)(orow + nb) = v;
        }
    }
}

extern "C" void kernel_launch(void* const* d_in, const int* in_sizes, int n_in,
                              void* d_out, int out_size, void* d_ws, size_t ws_size,
                              hipStream_t stream) {
    const float* x1 = (const float*)d_in[0];
    const float* x2 = (const float*)d_in[1];
    const float* c1 = (const float*)d_in[2];
    const float* c2 = (const float*)d_in[3];
    const int* lv   = (const int*)d_in[4];
    float* out = (float*)d_out;

    // workspace: qA codes 4MB @ 0, qB^T codes 4MB @ +4MB (needs ws >= 8MB)
    unsigned short* qA = (unsigned short*)d_ws;
    unsigned short* qB = qA + (size_t)BATCH * MDIM * KDIM;

    quant_both<<<QA_BLOCKS + BATCH * (NDIM / 64), 256, 0, stream>>>(
        x1, x2, qA, qB, c1, c2, lv);
    gemm_q<<<dim3(NDIM / 128, MDIM / 128, BATCH), 256, 0, stream>>>(
        qA, qB, c1, c2, lv, out);
}